// Round 8
// baseline (257.505 us; speedup 1.0000x reference)
//
#include <hip/hip_runtime.h>
#include <math.h>

#define NN 50000
#define NE 800000
#define IN_F 256
#define HF 256   // H*F
#define NH 8
#define NEG_SLOPE 0.2f

#define DEG_PAD 57344     // 7 * 8192, scan processes 8192/iter unguarded
#define GEMM_BLOCKS 782   // ceil(50000/64)
#define EDGE_BLOCKS 3125  // 800000/256
#define ELR_BLOCKS 12500  // 50000/4

typedef short bf16x8 __attribute__((ext_vector_type(8)));
typedef float f32x16 __attribute__((ext_vector_type(16)));

__device__ __forceinline__ unsigned short f2bf(float x) {
    unsigned u = __float_as_uint(x);
    u += 0x7FFF + ((u >> 16) & 1);          // round-to-nearest-even
    return (unsigned short)(u >> 16);
}
__device__ __forceinline__ float bf2f(unsigned short b) {
    return __uint_as_float(((unsigned)b) << 16);
}

// ---- L0: degree count + W -> swizzled bf16 (blocks 0..255 also convert) ----
__global__ void wdeg_kernel(const float* __restrict__ W,
                            unsigned short* __restrict__ Wb_hi,
                            const int* __restrict__ dst, int* __restrict__ deg) {
    int e = blockIdx.x * 256 + threadIdx.x;
    if (e < NE) atomicAdd(&deg[dst[e]], 1);
    if (e < IN_F * HF) {
        int k = e >> 8, n = e & 255;
        float x = W[e];
        int kt = k >> 5, kk = k & 31, c = kk >> 3, j = kk & 7;
        int slot = c ^ (n & 3);
        Wb_hi[((size_t)(kt * 256 + n)) * 32 + slot * 8 + j] = f2bf(x);
    }
}

// ---- L1: gemm (blocks 0..781) || scan (block 782, 256 thr, 32/thread) ------
__global__ __launch_bounds__(256) void gemm_scan_kernel(const float* __restrict__ feat,
                                                        const unsigned short* __restrict__ Wb_hi,
                                                        unsigned short* __restrict__ h,
                                                        const int* __restrict__ deg,
                                                        int* __restrict__ row_ptr,
                                                        int* __restrict__ cursor, int M) {
    __shared__ __align__(16) unsigned short As_hi[64][32];
    __shared__ __align__(16) unsigned short As_lo[64][32];
    __shared__ __align__(16) unsigned short Bs_hi[256][32];
    __shared__ int wsum[4];

    const int bid = blockIdx.x;
    if (bid >= GEMM_BLOCKS) {
        // ---- scan: one block, 256 threads, 32 elements/thread, 7 iters ----
        int tid = threadIdx.x, lane = tid & 63, wid = tid >> 6;
        int carry = 0;
        if (tid == 0) row_ptr[0] = 0;
        for (int base = 0; base < DEG_PAD; base += 8192) {
            int i0 = base + tid * 32;
            int v[32];
            #pragma unroll
            for (int q = 0; q < 8; ++q) {
                int4 a = *(const int4*)&deg[i0 + q * 4];
                v[q * 4 + 0] = a.x; v[q * 4 + 1] = a.y;
                v[q * 4 + 2] = a.z; v[q * 4 + 3] = a.w;
            }
            int s = 0;
            #pragma unroll
            for (int j = 0; j < 32; ++j) s += v[j];
            int x = s;
            #pragma unroll
            for (int off = 1; off < 64; off <<= 1) {
                int y = __shfl_up(x, off);
                if (lane >= off) x += y;
            }
            if (lane == 63) wsum[wid] = x;
            __syncthreads();
            int wadd = 0, tot = 0;
            #pragma unroll
            for (int w = 0; w < 4; ++w) {
                int t = wsum[w];
                tot += t;
                if (w < wid) wadd += t;
            }
            int r = carry + wadd + (x - s);
            #pragma unroll
            for (int j = 0; j < 32; ++j) {
                int i = i0 + j;
                if (i < NN) { cursor[i] = r; row_ptr[i + 1] = r + v[j]; }
                r += v[j];
            }
            carry += tot;
            __syncthreads();
        }
        return;
    }

    // ---- gemm: h_bf16 = bf16(feat @ W), 2-term bf16-split MFMA ----
    const int tid = threadIdx.x;
    const int lane = tid & 63;
    const int wid = tid >> 6;
    const int bm = bid * 64;

    f32x16 acc[2][2];
    #pragma unroll
    for (int mi = 0; mi < 2; ++mi)
        #pragma unroll
        for (int ni = 0; ni < 2; ++ni)
            #pragma unroll
            for (int r = 0; r < 16; ++r) acc[mi][ni][r] = 0.f;

    const int arow = tid >> 2;
    const int achk = tid & 3;
    const int aslot = achk ^ (arow & 3);
    const int grow = bm + arow;
    const float* aptr = feat + (size_t)grow * IN_F + achk * 8;

    for (int kt = 0; kt < 8; ++kt) {
        __syncthreads();
        float4 f0 = make_float4(0.f, 0.f, 0.f, 0.f), f1 = f0;
        if (grow < M) {
            f0 = *(const float4*)(aptr + kt * 32);
            f1 = *(const float4*)(aptr + kt * 32 + 4);
        }
        float xs[8] = {f0.x, f0.y, f0.z, f0.w, f1.x, f1.y, f1.z, f1.w};
        unsigned hi2[4], lo2[4];
        #pragma unroll
        for (int p = 0; p < 4; ++p) {
            unsigned short h0 = f2bf(xs[2 * p]), h1 = f2bf(xs[2 * p + 1]);
            unsigned short l0 = f2bf(xs[2 * p] - bf2f(h0));
            unsigned short l1 = f2bf(xs[2 * p + 1] - bf2f(h1));
            hi2[p] = (unsigned)h0 | ((unsigned)h1 << 16);
            lo2[p] = (unsigned)l0 | ((unsigned)l1 << 16);
        }
        *(int4*)&As_hi[arow][aslot * 8] = make_int4(hi2[0], hi2[1], hi2[2], hi2[3]);
        *(int4*)&As_lo[arow][aslot * 8] = make_int4(lo2[0], lo2[1], lo2[2], lo2[3]);
        {
            const int4* gh = (const int4*)(Wb_hi + (size_t)kt * 8192) + tid * 4;
            int4* dh = (int4*)&Bs_hi[tid][0];
            #pragma unroll
            for (int q = 0; q < 4; ++q) dh[q] = gh[q];
        }
        __syncthreads();
        #pragma unroll
        for (int ksc = 0; ksc < 2; ++ksc) {
            bf16x8 ah[2], av[2], bh[2];
            const int kc = ksc * 2 + (lane >> 5);
            #pragma unroll
            for (int mi = 0; mi < 2; ++mi) {
                int r = mi * 32 + (lane & 31);
                int slot = kc ^ (r & 3);
                ah[mi] = *(const bf16x8*)&As_hi[r][slot * 8];
                av[mi] = *(const bf16x8*)&As_lo[r][slot * 8];
            }
            #pragma unroll
            for (int ni = 0; ni < 2; ++ni) {
                int n = wid * 64 + ni * 32 + (lane & 31);
                int slot = kc ^ (n & 3);
                bh[ni] = *(const bf16x8*)&Bs_hi[n][slot * 8];
            }
            #pragma unroll
            for (int mi = 0; mi < 2; ++mi)
                #pragma unroll
                for (int ni = 0; ni < 2; ++ni) {
                    acc[mi][ni] = __builtin_amdgcn_mfma_f32_32x32x16_bf16(ah[mi], bh[ni], acc[mi][ni], 0, 0, 0);
                    acc[mi][ni] = __builtin_amdgcn_mfma_f32_32x32x16_bf16(av[mi], bh[ni], acc[mi][ni], 0, 0, 0);
                }
        }
    }
    #pragma unroll
    for (int mi = 0; mi < 2; ++mi)
        #pragma unroll
        for (int ni = 0; ni < 2; ++ni)
            #pragma unroll
            for (int r = 0; r < 16; ++r) {
                int row = mi * 32 + (r & 3) + 8 * (r >> 2) + 4 * (lane >> 5);
                int col = wid * 64 + ni * 32 + (lane & 31);
                int gr = bm + row;
                if (gr < M) h[(size_t)gr * HF + col] = f2bf(acc[mi][ni][r]);
            }
}

// ---- L2: elr (blocks 0..12499) || fill (blocks 12500..15624) ---------------
__global__ __launch_bounds__(256) void elr_fill_kernel(const unsigned short* __restrict__ h,
                                                       const float* __restrict__ al,
                                                       const float* __restrict__ ar,
                                                       float* __restrict__ el,
                                                       float* __restrict__ er,
                                                       const int* __restrict__ src,
                                                       const int* __restrict__ dst,
                                                       int* __restrict__ cursor,
                                                       int* __restrict__ csr_src) {
    int bid = blockIdx.x;
    if (bid >= ELR_BLOCKS) {
        int e = (bid - ELR_BLOCKS) * 256 + threadIdx.x;
        if (e < NE) {
            int pos = atomicAdd(&cursor[dst[e]], 1);
            csr_src[pos] = src[e];
        }
        return;
    }
    int node = bid * 4 + (threadIdx.x >> 6);
    if (node >= NN) return;
    int lane = threadIdx.x & 63;
    short4 hv = *(const short4*)&h[(size_t)node * HF + lane * 4];
    float h0 = bf2f((unsigned short)hv.x), h1 = bf2f((unsigned short)hv.y);
    float h2 = bf2f((unsigned short)hv.z), h3 = bf2f((unsigned short)hv.w);
    float4 alv = *(const float4*)&al[lane * 4];
    float4 arv = *(const float4*)&ar[lane * 4];
    float pl = h0 * alv.x + h1 * alv.y + h2 * alv.z + h3 * alv.w;
    float pr = h0 * arv.x + h1 * arv.y + h2 * arv.z + h3 * arv.w;
    #pragma unroll
    for (int off = 1; off < 8; off <<= 1) {
        pl += __shfl_xor(pl, off);
        pr += __shfl_xor(pr, off);
    }
    if ((lane & 7) == 0) {
        el[node * NH + (lane >> 3)] = pl;
        er[node * NH + (lane >> 3)] = pr;
    }
}

// ---- L3: single-pass aggregate: lane = edge_slot(3b) x head(3b), 16/iter ---
__global__ __launch_bounds__(256) void agg_kernel(const unsigned short* __restrict__ h,
                                                  const float* __restrict__ el,
                                                  const float* __restrict__ er,
                                                  const int* __restrict__ row_ptr,
                                                  const int* __restrict__ csr_src,
                                                  const float* __restrict__ bias,
                                                  float* __restrict__ out) {
    int node = blockIdx.x * 4 + (threadIdx.x >> 6);
    if (node >= NN) return;
    int lane = threadIdx.x & 63;
    int eg = lane >> 3;        // edge slot
    int fg = lane & 7;         // head (32 features)
    int beg = row_ptr[node];
    int end = row_ptr[node + 1];
    float er_mine = er[(size_t)node * NH + fg];

    float ssum = 0.f;
    float acc[32];
    #pragma unroll
    for (int j = 0; j < 32; ++j) acc[j] = 0.f;

    for (int i0 = beg; i0 < end; i0 += 16) {
        int idxA = i0 + eg;
        int idxB = i0 + 8 + eg;
        bool vA = idxA < end, vB = idxB < end;
        int sA = csr_src[vA ? idxA : beg];
        int sB = csr_src[vB ? idxB : beg];
        float eA = el[(size_t)sA * NH + fg] + er_mine;
        float eB = el[(size_t)sB * NH + fg] + er_mine;
        eA = eA > 0.f ? eA : NEG_SLOPE * eA;
        eB = eB > 0.f ? eB : NEG_SLOPE * eB;
        float pA = vA ? __expf(eA) : 0.f;
        float pB = vB ? __expf(eB) : 0.f;
        ssum += pA + pB;
        const unsigned short* hpA = h + (size_t)sA * HF + fg * 32;
        const unsigned short* hpB = h + (size_t)sB * HF + fg * 32;
        bf16x8 va[4], vb[4];
        #pragma unroll
        for (int c = 0; c < 4; ++c) { va[c] = *(const bf16x8*)(hpA + c * 8); }
        #pragma unroll
        for (int c = 0; c < 4; ++c) { vb[c] = *(const bf16x8*)(hpB + c * 8); }
        #pragma unroll
        for (int c = 0; c < 4; ++c)
            #pragma unroll
            for (int k = 0; k < 8; ++k) {
                acc[c * 8 + k] = fmaf(bf2f((unsigned short)va[c][k]), pA, acc[c * 8 + k]);
                acc[c * 8 + k] = fmaf(bf2f((unsigned short)vb[c][k]), pB, acc[c * 8 + k]);
            }
    }

    // reduce ssum over edge slots (keep head bits)
    ssum += __shfl_xor(ssum, 8);
    ssum += __shfl_xor(ssum, 16);
    ssum += __shfl_xor(ssum, 32);
    float inv_s = (ssum > 0.f) ? 1.f / ssum : 0.f;

    // recursive-halving reduce-scatter over eg (static reg indices only)
    int e2 = (lane >> 5) & 1, e1 = (lane >> 4) & 1, e0 = (lane >> 3) & 1;
    float t16[16];
    #pragma unroll
    for (int j = 0; j < 16; ++j) {
        float keep = e2 ? acc[16 + j] : acc[j];
        float send = e2 ? acc[j] : acc[16 + j];
        t16[j] = keep + __shfl_xor(send, 32);
    }
    float t8[8];
    #pragma unroll
    for (int j = 0; j < 8; ++j) {
        float keep = e1 ? t16[8 + j] : t16[j];
        float send = e1 ? t16[j] : t16[8 + j];
        t8[j] = keep + __shfl_xor(send, 16);
    }
    float t4[4];
    #pragma unroll
    for (int j = 0; j < 4; ++j) {
        float keep = e0 ? t8[4 + j] : t8[j];
        float send = e0 ? t8[j] : t8[4 + j];
        t4[j] = keep + __shfl_xor(send, 8);
    }

    int col = fg * 32 + eg * 4;
    float4 bv = *(const float4*)&bias[col];
    float4 o = make_float4(fmaf(t4[0], inv_s, bv.x), fmaf(t4[1], inv_s, bv.y),
                           fmaf(t4[2], inv_s, bv.z), fmaf(t4[3], inv_s, bv.w));
    *(float4*)&out[(size_t)node * HF + col] = o;
}

extern "C" void kernel_launch(void* const* d_in, const int* in_sizes, int n_in,
                              void* d_out, int out_size, void* d_ws, size_t ws_size,
                              hipStream_t stream) {
    const float* feat = (const float*)d_in[0];
    const float* W    = (const float*)d_in[1];
    const float* al   = (const float*)d_in[2];
    const float* ar   = (const float*)d_in[3];
    const float* bias = (const float*)d_in[4];
    const int*   src  = (const int*)d_in[5];
    const int*   dst  = (const int*)d_in[6];
    float* out = (float*)d_out;

    char* ws = (char*)d_ws;
    size_t off = 0;
    unsigned short* h = (unsigned short*)(ws + off); off += (size_t)NN * HF * 2;     // 25.6 MB
    float* el = (float*)(ws + off);                  off += (size_t)NN * NH * 4;
    float* er = (float*)(ws + off);                  off += (size_t)NN * NH * 4;
    int* deg = (int*)(ws + off);                     off += (size_t)DEG_PAD * 4;
    int* row_ptr = (int*)(ws + off);                 off += (size_t)(NN + 1) * 4 + 60;
    off &= ~(size_t)63;
    int* cursor = (int*)(ws + off);                  off += (size_t)NN * 4;
    int* csr_src = (int*)(ws + off);                 off += (size_t)NE * 4;
    unsigned short* Wb_hi = (unsigned short*)(ws + off); off += (size_t)IN_F * HF * 2;

    hipMemsetAsync(deg, 0, (size_t)DEG_PAD * 4, stream);

    wdeg_kernel<<<EDGE_BLOCKS, 256, 0, stream>>>(W, Wb_hi, dst, deg);
    gemm_scan_kernel<<<GEMM_BLOCKS + 1, 256, 0, stream>>>(feat, Wb_hi, h, deg, row_ptr, cursor, NN);
    elr_fill_kernel<<<ELR_BLOCKS + EDGE_BLOCKS, 256, 0, stream>>>(h, al, ar, el, er, src, dst, cursor, csr_src);
    agg_kernel<<<ELR_BLOCKS, 256, 0, stream>>>(h, el, er, row_ptr, csr_src, bias, out);
}

// Round 9
// 256.728 us; speedup vs baseline: 1.0030x; 1.0030x over previous
//
#include <hip/hip_runtime.h>
#include <math.h>

#define NN 50000
#define NE 800000
#define IN_F 256
#define HF 256   // H*F
#define NH 8
#define NEG_SLOPE 0.2f

#define DEG_PAD 57344     // 7 * 8192, scan processes 8192/iter unguarded
#define GEMM_BLOCKS 782   // ceil(50000/64)
#define EDGE_BLOCKS 3125  // 800000/256
#define ELR_BLOCKS 12500  // 50000/4

typedef short bf16x8 __attribute__((ext_vector_type(8)));
typedef float f32x16 __attribute__((ext_vector_type(16)));

__device__ __forceinline__ unsigned short f2bf(float x) {
    unsigned u = __float_as_uint(x);
    u += 0x7FFF + ((u >> 16) & 1);          // round-to-nearest-even
    return (unsigned short)(u >> 16);
}
__device__ __forceinline__ float bf2f(unsigned short b) {
    return __uint_as_float(((unsigned)b) << 16);
}

// ---- L0: degree count + W -> linear K-blocked bf16 -------------------------
// Wb[(kt*256 + n)*32 + kk] = bf16(W[(kt*32+kk)*256 + n])
__global__ void wdeg_kernel(const float* __restrict__ W,
                            unsigned short* __restrict__ Wb,
                            const int* __restrict__ dst, int* __restrict__ deg) {
    int e = blockIdx.x * 256 + threadIdx.x;
    if (e < NE) atomicAdd(&deg[dst[e]], 1);
    if (e < IN_F * HF) {
        int k = e >> 8, n = e & 255;
        float x = W[e];
        int kt = k >> 5, kk = k & 31;
        Wb[((size_t)(kt * 256 + n)) * 32 + kk] = f2bf(x);
    }
}

// ---- L1: gemm (blocks 0..781) || scan (block 782) --------------------------
// gemm: h = bf16(feat @ W), 2-term bf16-split MFMA, A-panel prefetched to regs,
// padded LDS (row stride 40 shorts -> conflict-free ds_read_b128), B from L2.
__global__ __launch_bounds__(256) void gemm_scan_kernel(const float* __restrict__ feat,
                                                        const unsigned short* __restrict__ Wb,
                                                        unsigned short* __restrict__ h,
                                                        const int* __restrict__ deg,
                                                        int* __restrict__ row_ptr,
                                                        int* __restrict__ cursor, int M) {
    __shared__ __align__(16) unsigned short As_hi[64][40];
    __shared__ __align__(16) unsigned short As_lo[64][40];
    __shared__ int wsum[4];

    const int bid = blockIdx.x;
    if (bid >= GEMM_BLOCKS) {
        // ---- scan: one block, 256 threads, 32 elements/thread, 7 iters ----
        int tid = threadIdx.x, lane = tid & 63, wid = tid >> 6;
        int carry = 0;
        if (tid == 0) row_ptr[0] = 0;
        for (int base = 0; base < DEG_PAD; base += 8192) {
            int i0 = base + tid * 32;
            int v[32];
            #pragma unroll
            for (int q = 0; q < 8; ++q) {
                int4 a = *(const int4*)&deg[i0 + q * 4];
                v[q * 4 + 0] = a.x; v[q * 4 + 1] = a.y;
                v[q * 4 + 2] = a.z; v[q * 4 + 3] = a.w;
            }
            int s = 0;
            #pragma unroll
            for (int j = 0; j < 32; ++j) s += v[j];
            int x = s;
            #pragma unroll
            for (int off = 1; off < 64; off <<= 1) {
                int y = __shfl_up(x, off);
                if (lane >= off) x += y;
            }
            if (lane == 63) wsum[wid] = x;
            __syncthreads();
            int wadd = 0, tot = 0;
            #pragma unroll
            for (int w = 0; w < 4; ++w) {
                int t = wsum[w];
                tot += t;
                if (w < wid) wadd += t;
            }
            int r = carry + wadd + (x - s);
            #pragma unroll
            for (int j = 0; j < 32; ++j) {
                int i = i0 + j;
                if (i < NN) { cursor[i] = r; row_ptr[i + 1] = r + v[j]; }
                r += v[j];
            }
            carry += tot;
            __syncthreads();
        }
        return;
    }

    const int tid = threadIdx.x;
    const int lane = tid & 63;
    const int wid = tid >> 6;
    const int bm = bid * 64;

    // ---- A panel: prefetch all K into registers (16 float4 in flight) ----
    const int arow = tid >> 2;
    const int achk = tid & 3;
    const int grow = bm + arow;
    const int crow = (grow < M) ? grow : 0;   // clamped rows never stored
    const float* ap = feat + (size_t)crow * IN_F + achk * 8;
    float4 a0[8], a1[8];
    #pragma unroll
    for (int kt = 0; kt < 8; ++kt) {
        a0[kt] = *(const float4*)(ap + kt * 32);
        a1[kt] = *(const float4*)(ap + kt * 32 + 4);
    }

    f32x16 acc[2][2];
    #pragma unroll
    for (int mi = 0; mi < 2; ++mi)
        #pragma unroll
        for (int ni = 0; ni < 2; ++ni)
            #pragma unroll
            for (int r = 0; r < 16; ++r) acc[mi][ni][r] = 0.f;

    const int khalf = lane >> 5;          // 0/1: k-chunk half within ksc
    const int nbase = wid * 64 + (lane & 31);

    for (int kt = 0; kt < 8; ++kt) {
        // ---- B fragments straight from L2 (issued before barrier) ----
        bf16x8 bh[2][2];   // [ksc][ni]
        #pragma unroll
        for (int ksc = 0; ksc < 2; ++ksc)
            #pragma unroll
            for (int ni = 0; ni < 2; ++ni)
                bh[ksc][ni] = *(const bf16x8*)(Wb
                    + ((size_t)(kt * 256) + nbase + ni * 32) * 32
                    + (ksc * 2 + khalf) * 8);

        // ---- stage A(kt): fp32 regs -> hi/lo bf16 -> LDS ----
        float xs[8] = {a0[kt].x, a0[kt].y, a0[kt].z, a0[kt].w,
                       a1[kt].x, a1[kt].y, a1[kt].z, a1[kt].w};
        unsigned hi2[4], lo2[4];
        #pragma unroll
        for (int p = 0; p < 4; ++p) {
            unsigned short h0 = f2bf(xs[2 * p]), h1 = f2bf(xs[2 * p + 1]);
            unsigned short l0 = f2bf(xs[2 * p] - bf2f(h0));
            unsigned short l1 = f2bf(xs[2 * p + 1] - bf2f(h1));
            hi2[p] = (unsigned)h0 | ((unsigned)h1 << 16);
            lo2[p] = (unsigned)l0 | ((unsigned)l1 << 16);
        }
        *(int4*)&As_hi[arow][achk * 8] = make_int4(hi2[0], hi2[1], hi2[2], hi2[3]);
        *(int4*)&As_lo[arow][achk * 8] = make_int4(lo2[0], lo2[1], lo2[2], lo2[3]);
        __syncthreads();

        // ---- MFMA ----
        #pragma unroll
        for (int ksc = 0; ksc < 2; ++ksc) {
            const int kchunk = ksc * 2 + khalf;
            bf16x8 ah[2], av[2];
            #pragma unroll
            for (int mi = 0; mi < 2; ++mi) {
                int r = mi * 32 + (lane & 31);
                ah[mi] = *(const bf16x8*)&As_hi[r][kchunk * 8];
                av[mi] = *(const bf16x8*)&As_lo[r][kchunk * 8];
            }
            #pragma unroll
            for (int mi = 0; mi < 2; ++mi)
                #pragma unroll
                for (int ni = 0; ni < 2; ++ni) {
                    acc[mi][ni] = __builtin_amdgcn_mfma_f32_32x32x16_bf16(ah[mi], bh[ksc][ni], acc[mi][ni], 0, 0, 0);
                    acc[mi][ni] = __builtin_amdgcn_mfma_f32_32x32x16_bf16(av[mi], bh[ksc][ni], acc[mi][ni], 0, 0, 0);
                }
        }
        __syncthreads();
    }

    // ---- epilogue: bf16 store ----
    #pragma unroll
    for (int mi = 0; mi < 2; ++mi)
        #pragma unroll
        for (int ni = 0; ni < 2; ++ni)
            #pragma unroll
            for (int r = 0; r < 16; ++r) {
                int row = mi * 32 + (r & 3) + 8 * (r >> 2) + 4 * (lane >> 5);
                int col = wid * 64 + ni * 32 + (lane & 31);
                int gr = bm + row;
                if (gr < M) h[(size_t)gr * HF + col] = f2bf(acc[mi][ni][r]);
            }
}

// ---- L2: elr (blocks 0..12499) || fill (blocks 12500..15624) ---------------
__global__ __launch_bounds__(256) void elr_fill_kernel(const unsigned short* __restrict__ h,
                                                       const float* __restrict__ al,
                                                       const float* __restrict__ ar,
                                                       float* __restrict__ el,
                                                       float* __restrict__ er,
                                                       const int* __restrict__ src,
                                                       const int* __restrict__ dst,
                                                       int* __restrict__ cursor,
                                                       int* __restrict__ csr_src) {
    int bid = blockIdx.x;
    if (bid >= ELR_BLOCKS) {
        int e = (bid - ELR_BLOCKS) * 256 + threadIdx.x;
        if (e < NE) {
            int pos = atomicAdd(&cursor[dst[e]], 1);
            csr_src[pos] = src[e];
        }
        return;
    }
    int node = bid * 4 + (threadIdx.x >> 6);
    if (node >= NN) return;
    int lane = threadIdx.x & 63;
    short4 hv = *(const short4*)&h[(size_t)node * HF + lane * 4];
    float h0 = bf2f((unsigned short)hv.x), h1 = bf2f((unsigned short)hv.y);
    float h2 = bf2f((unsigned short)hv.z), h3 = bf2f((unsigned short)hv.w);
    float4 alv = *(const float4*)&al[lane * 4];
    float4 arv = *(const float4*)&ar[lane * 4];
    float pl = h0 * alv.x + h1 * alv.y + h2 * alv.z + h3 * alv.w;
    float pr = h0 * arv.x + h1 * arv.y + h2 * arv.z + h3 * arv.w;
    #pragma unroll
    for (int off = 1; off < 8; off <<= 1) {
        pl += __shfl_xor(pl, off);
        pr += __shfl_xor(pr, off);
    }
    if ((lane & 7) == 0) {
        el[node * NH + (lane >> 3)] = pl;
        er[node * NH + (lane >> 3)] = pr;
    }
}

// ---- L3: single-pass aggregate: lane = edge_slot(3b) x head(3b), 16/iter ---
__global__ __launch_bounds__(256) void agg_kernel(const unsigned short* __restrict__ h,
                                                  const float* __restrict__ el,
                                                  const float* __restrict__ er,
                                                  const int* __restrict__ row_ptr,
                                                  const int* __restrict__ csr_src,
                                                  const float* __restrict__ bias,
                                                  float* __restrict__ out) {
    int node = blockIdx.x * 4 + (threadIdx.x >> 6);
    if (node >= NN) return;
    int lane = threadIdx.x & 63;
    int eg = lane >> 3;        // edge slot
    int fg = lane & 7;         // head (32 features)
    int beg = row_ptr[node];
    int end = row_ptr[node + 1];
    float er_mine = er[(size_t)node * NH + fg];

    float ssum = 0.f;
    float acc[32];
    #pragma unroll
    for (int j = 0; j < 32; ++j) acc[j] = 0.f;

    for (int i0 = beg; i0 < end; i0 += 16) {
        int idxA = i0 + eg;
        int idxB = i0 + 8 + eg;
        bool vA = idxA < end, vB = idxB < end;
        int sA = csr_src[vA ? idxA : beg];
        int sB = csr_src[vB ? idxB : beg];
        float eA = el[(size_t)sA * NH + fg] + er_mine;
        float eB = el[(size_t)sB * NH + fg] + er_mine;
        eA = eA > 0.f ? eA : NEG_SLOPE * eA;
        eB = eB > 0.f ? eB : NEG_SLOPE * eB;
        float pA = vA ? __expf(eA) : 0.f;
        float pB = vB ? __expf(eB) : 0.f;
        ssum += pA + pB;
        const unsigned short* hpA = h + (size_t)sA * HF + fg * 32;
        const unsigned short* hpB = h + (size_t)sB * HF + fg * 32;
        bf16x8 va[4], vb[4];
        #pragma unroll
        for (int c = 0; c < 4; ++c) { va[c] = *(const bf16x8*)(hpA + c * 8); }
        #pragma unroll
        for (int c = 0; c < 4; ++c) { vb[c] = *(const bf16x8*)(hpB + c * 8); }
        #pragma unroll
        for (int c = 0; c < 4; ++c)
            #pragma unroll
            for (int k = 0; k < 8; ++k) {
                acc[c * 8 + k] = fmaf(bf2f((unsigned short)va[c][k]), pA, acc[c * 8 + k]);
                acc[c * 8 + k] = fmaf(bf2f((unsigned short)vb[c][k]), pB, acc[c * 8 + k]);
            }
    }

    // reduce ssum over edge slots (keep head bits)
    ssum += __shfl_xor(ssum, 8);
    ssum += __shfl_xor(ssum, 16);
    ssum += __shfl_xor(ssum, 32);
    float inv_s = (ssum > 0.f) ? 1.f / ssum : 0.f;

    // recursive-halving reduce-scatter over eg (static reg indices only)
    int e2 = (lane >> 5) & 1, e1 = (lane >> 4) & 1, e0 = (lane >> 3) & 1;
    float t16[16];
    #pragma unroll
    for (int j = 0; j < 16; ++j) {
        float keep = e2 ? acc[16 + j] : acc[j];
        float send = e2 ? acc[j] : acc[16 + j];
        t16[j] = keep + __shfl_xor(send, 32);
    }
    float t8[8];
    #pragma unroll
    for (int j = 0; j < 8; ++j) {
        float keep = e1 ? t16[8 + j] : t16[j];
        float send = e1 ? t16[j] : t16[8 + j];
        t8[j] = keep + __shfl_xor(send, 16);
    }
    float t4[4];
    #pragma unroll
    for (int j = 0; j < 4; ++j) {
        float keep = e0 ? t8[4 + j] : t8[j];
        float send = e0 ? t8[j] : t8[4 + j];
        t4[j] = keep + __shfl_xor(send, 8);
    }

    int col = fg * 32 + eg * 4;
    float4 bv = *(const float4*)&bias[col];
    float4 o = make_float4(fmaf(t4[0], inv_s, bv.x), fmaf(t4[1], inv_s, bv.y),
                           fmaf(t4[2], inv_s, bv.z), fmaf(t4[3], inv_s, bv.w));
    *(float4*)&out[(size_t)node * HF + col] = o;
}

extern "C" void kernel_launch(void* const* d_in, const int* in_sizes, int n_in,
                              void* d_out, int out_size, void* d_ws, size_t ws_size,
                              hipStream_t stream) {
    const float* feat = (const float*)d_in[0];
    const float* W    = (const float*)d_in[1];
    const float* al   = (const float*)d_in[2];
    const float* ar   = (const float*)d_in[3];
    const float* bias = (const float*)d_in[4];
    const int*   src  = (const int*)d_in[5];
    const int*   dst  = (const int*)d_in[6];
    float* out = (float*)d_out;

    char* ws = (char*)d_ws;
    size_t off = 0;
    unsigned short* h = (unsigned short*)(ws + off); off += (size_t)NN * HF * 2;     // 25.6 MB
    float* el = (float*)(ws + off);                  off += (size_t)NN * NH * 4;
    float* er = (float*)(ws + off);                  off += (size_t)NN * NH * 4;
    int* deg = (int*)(ws + off);                     off += (size_t)DEG_PAD * 4;
    int* row_ptr = (int*)(ws + off);                 off += (size_t)(NN + 1) * 4 + 60;
    off &= ~(size_t)63;
    int* cursor = (int*)(ws + off);                  off += (size_t)NN * 4;
    int* csr_src = (int*)(ws + off);                 off += (size_t)NE * 4;
    unsigned short* Wb = (unsigned short*)(ws + off); off += (size_t)IN_F * HF * 2;

    hipMemsetAsync(deg, 0, (size_t)DEG_PAD * 4, stream);

    wdeg_kernel<<<EDGE_BLOCKS, 256, 0, stream>>>(W, Wb, dst, deg);
    gemm_scan_kernel<<<GEMM_BLOCKS + 1, 256, 0, stream>>>(feat, Wb, h, deg, row_ptr, cursor, NN);
    elr_fill_kernel<<<ELR_BLOCKS + EDGE_BLOCKS, 256, 0, stream>>>(h, al, ar, el, er, src, dst, cursor, csr_src);
    agg_kernel<<<ELR_BLOCKS, 256, 0, stream>>>(h, el, er, row_ptr, csr_src, bias, out);
}

// Round 10
// 211.903 us; speedup vs baseline: 1.2152x; 1.2115x over previous
//
#include <hip/hip_runtime.h>
#include <math.h>

#define NN 50000
#define NE 800000
#define IN_F 256
#define HF 256   // H*F
#define NH 8
#define NEG_SLOPE 0.2f

#define DEG_PAD 57344     // 7 * 8192, scan processes 8192/iter unguarded
#define GEMM_BLOCKS 782   // ceil(50000/64)
#define EDGE_BLOCKS 3125  // 800000/256
#define ELR_BLOCKS 12500  // 50000/4

typedef short bf16x8 __attribute__((ext_vector_type(8)));
typedef float f32x16 __attribute__((ext_vector_type(16)));

__device__ __forceinline__ unsigned short f2bf(float x) {
    unsigned u = __float_as_uint(x);
    u += 0x7FFF + ((u >> 16) & 1);          // round-to-nearest-even
    return (unsigned short)(u >> 16);
}
__device__ __forceinline__ float bf2f(unsigned short b) {
    return __uint_as_float(((unsigned)b) << 16);
}

// ---- degree count + W -> linear K-blocked bf16 ------------------------------
// Wb[(kt*256 + n)*32 + kk] = bf16(W[(kt*32+kk)*256 + n])
__global__ void wdeg_kernel(const float* __restrict__ W,
                            unsigned short* __restrict__ Wb,
                            const int* __restrict__ dst, int* __restrict__ deg) {
    int e = blockIdx.x * 256 + threadIdx.x;
    if (e < NE) atomicAdd(&deg[dst[e]], 1);
    if (e < IN_F * HF) {
        int k = e >> 8, n = e & 255;
        float x = W[e];
        int kt = k >> 5, kk = k & 31;
        Wb[((size_t)(kt * 256 + n)) * 32 + kk] = f2bf(x);
    }
}

// ---- GEMM standalone: h = bf16(feat @ W), 2-term bf16-split MFMA ------------
// A: one-deep register double buffer -> padded LDS (stride 40, conflict-free).
// B: 16B fragments straight from L2 (Wb is 128 KB, L2-hot).
__global__ __launch_bounds__(256) void gemm_kernel(const float* __restrict__ feat,
                                                   const unsigned short* __restrict__ Wb,
                                                   unsigned short* __restrict__ h, int M) {
    __shared__ __align__(16) unsigned short As_hi[64][40];
    __shared__ __align__(16) unsigned short As_lo[64][40];

    const int tid = threadIdx.x;
    const int lane = tid & 63;
    const int wid = tid >> 6;
    const int bm = blockIdx.x * 64;

    const int arow = tid >> 2;
    const int achk = tid & 3;
    const int grow = bm + arow;
    const int crow = (grow < M) ? grow : 0;   // clamped rows never stored
    const float* ap = feat + (size_t)crow * IN_F + achk * 8;

    f32x16 acc[2][2];
    #pragma unroll
    for (int mi = 0; mi < 2; ++mi)
        #pragma unroll
        for (int ni = 0; ni < 2; ++ni)
            #pragma unroll
            for (int r = 0; r < 16; ++r) acc[mi][ni][r] = 0.f;

    const int khalf = lane >> 5;          // 0/1
    const int nbase = wid * 64 + (lane & 31);

    float4 cur0 = *(const float4*)(ap);
    float4 cur1 = *(const float4*)(ap + 4);

    for (int kt = 0; kt < 8; ++kt) {
        // prefetch next kt's A chunk (one-deep double buffer)
        float4 nxt0, nxt1;
        if (kt < 7) {
            nxt0 = *(const float4*)(ap + (kt + 1) * 32);
            nxt1 = *(const float4*)(ap + (kt + 1) * 32 + 4);
        }
        // B fragments from L2, issued early
        bf16x8 bh[2][2];   // [ksc][ni]
        #pragma unroll
        for (int ksc = 0; ksc < 2; ++ksc)
            #pragma unroll
            for (int ni = 0; ni < 2; ++ni)
                bh[ksc][ni] = *(const bf16x8*)(Wb
                    + ((size_t)(kt * 256) + nbase + ni * 32) * 32
                    + (ksc * 2 + khalf) * 8);

        // stage A(kt): fp32 regs -> hi/lo bf16 -> LDS
        float xs[8] = {cur0.x, cur0.y, cur0.z, cur0.w, cur1.x, cur1.y, cur1.z, cur1.w};
        unsigned hi2[4], lo2[4];
        #pragma unroll
        for (int p = 0; p < 4; ++p) {
            unsigned short h0 = f2bf(xs[2 * p]), h1 = f2bf(xs[2 * p + 1]);
            unsigned short l0 = f2bf(xs[2 * p] - bf2f(h0));
            unsigned short l1 = f2bf(xs[2 * p + 1] - bf2f(h1));
            hi2[p] = (unsigned)h0 | ((unsigned)h1 << 16);
            lo2[p] = (unsigned)l0 | ((unsigned)l1 << 16);
        }
        *(int4*)&As_hi[arow][achk * 8] = make_int4(hi2[0], hi2[1], hi2[2], hi2[3]);
        *(int4*)&As_lo[arow][achk * 8] = make_int4(lo2[0], lo2[1], lo2[2], lo2[3]);
        __syncthreads();

        #pragma unroll
        for (int ksc = 0; ksc < 2; ++ksc) {
            const int kchunk = ksc * 2 + khalf;
            bf16x8 ah[2], av[2];
            #pragma unroll
            for (int mi = 0; mi < 2; ++mi) {
                int r = mi * 32 + (lane & 31);
                ah[mi] = *(const bf16x8*)&As_hi[r][kchunk * 8];
                av[mi] = *(const bf16x8*)&As_lo[r][kchunk * 8];
            }
            #pragma unroll
            for (int mi = 0; mi < 2; ++mi)
                #pragma unroll
                for (int ni = 0; ni < 2; ++ni) {
                    acc[mi][ni] = __builtin_amdgcn_mfma_f32_32x32x16_bf16(ah[mi], bh[ksc][ni], acc[mi][ni], 0, 0, 0);
                    acc[mi][ni] = __builtin_amdgcn_mfma_f32_32x32x16_bf16(av[mi], bh[ksc][ni], acc[mi][ni], 0, 0, 0);
                }
        }
        __syncthreads();
        cur0 = nxt0;
        cur1 = nxt1;
    }

    #pragma unroll
    for (int mi = 0; mi < 2; ++mi)
        #pragma unroll
        for (int ni = 0; ni < 2; ++ni)
            #pragma unroll
            for (int r = 0; r < 16; ++r) {
                int row = mi * 32 + (r & 3) + 8 * (r >> 2) + 4 * (lane >> 5);
                int col = wid * 64 + ni * 32 + (lane & 31);
                int gr = bm + row;
                if (gr < M) h[(size_t)gr * HF + col] = f2bf(acc[mi][ni][r]);
            }
}

// ---- el/er per node ----------------------------------------------------------
__global__ __launch_bounds__(256) void elr_kernel(const unsigned short* __restrict__ h,
                                                  const float* __restrict__ al,
                                                  const float* __restrict__ ar,
                                                  float* __restrict__ el,
                                                  float* __restrict__ er) {
    int node = blockIdx.x * 4 + (threadIdx.x >> 6);
    if (node >= NN) return;
    int lane = threadIdx.x & 63;
    short4 hv = *(const short4*)&h[(size_t)node * HF + lane * 4];
    float h0 = bf2f((unsigned short)hv.x), h1 = bf2f((unsigned short)hv.y);
    float h2 = bf2f((unsigned short)hv.z), h3 = bf2f((unsigned short)hv.w);
    float4 alv = *(const float4*)&al[lane * 4];
    float4 arv = *(const float4*)&ar[lane * 4];
    float pl = h0 * alv.x + h1 * alv.y + h2 * alv.z + h3 * alv.w;
    float pr = h0 * arv.x + h1 * arv.y + h2 * arv.z + h3 * arv.w;
    #pragma unroll
    for (int off = 1; off < 8; off <<= 1) {
        pl += __shfl_xor(pl, off);
        pr += __shfl_xor(pr, off);
    }
    if ((lane & 7) == 0) {
        el[node * NH + (lane >> 3)] = pl;
        er[node * NH + (lane >> 3)] = pr;
    }
}

// ---- scan: single block, 1024 threads, 8/thread, 7 iterations ---------------
__global__ __launch_bounds__(1024) void scan_kernel(const int* __restrict__ deg,
                                                    int* __restrict__ row_ptr,
                                                    int* __restrict__ cursor) {
    __shared__ int wsum[16];
    int tid = threadIdx.x, lane = tid & 63, wid = tid >> 6;
    int carry = 0;
    if (tid == 0) row_ptr[0] = 0;
    for (int base = 0; base < DEG_PAD; base += 8192) {
        int i0 = base + tid * 8;
        int4 a = *(const int4*)&deg[i0];
        int4 b = *(const int4*)&deg[i0 + 4];
        int v[8] = {a.x, a.y, a.z, a.w, b.x, b.y, b.z, b.w};
        int s8 = 0;
        #pragma unroll
        for (int j = 0; j < 8; ++j) s8 += v[j];
        int x = s8;
        #pragma unroll
        for (int off = 1; off < 64; off <<= 1) {
            int y = __shfl_up(x, off);
            if (lane >= off) x += y;
        }
        if (lane == 63) wsum[wid] = x;
        __syncthreads();
        int wadd = 0, tot = 0;
        #pragma unroll
        for (int w = 0; w < 16; ++w) {
            int s = wsum[w];
            tot += s;
            if (w < wid) wadd += s;
        }
        int r = carry + wadd + (x - s8);
        #pragma unroll
        for (int j = 0; j < 8; ++j) {
            int i = i0 + j;
            if (i < NN) { cursor[i] = r; row_ptr[i + 1] = r + v[j]; }
            r += v[j];
        }
        carry += tot;
        __syncthreads();
    }
}

// ---- fill CSR ----------------------------------------------------------------
__global__ void fill_kernel(const int* __restrict__ src, const int* __restrict__ dst,
                            int* __restrict__ cursor, int* __restrict__ csr_src) {
    int e = blockIdx.x * 256 + threadIdx.x;
    if (e < NE) {
        int pos = atomicAdd(&cursor[dst[e]], 1);
        csr_src[pos] = src[e];
    }
}

// ---- single-pass aggregate: lane = edge_slot(3b) x head(3b), 16/iter --------
__global__ __launch_bounds__(256) void agg_kernel(const unsigned short* __restrict__ h,
                                                  const float* __restrict__ el,
                                                  const float* __restrict__ er,
                                                  const int* __restrict__ row_ptr,
                                                  const int* __restrict__ csr_src,
                                                  const float* __restrict__ bias,
                                                  float* __restrict__ out) {
    int node = blockIdx.x * 4 + (threadIdx.x >> 6);
    if (node >= NN) return;
    int lane = threadIdx.x & 63;
    int eg = lane >> 3;        // edge slot
    int fg = lane & 7;         // head (32 features)
    int beg = row_ptr[node];
    int end = row_ptr[node + 1];
    float er_mine = er[(size_t)node * NH + fg];

    float ssum = 0.f;
    float acc[32];
    #pragma unroll
    for (int j = 0; j < 32; ++j) acc[j] = 0.f;

    for (int i0 = beg; i0 < end; i0 += 16) {
        int idxA = i0 + eg;
        int idxB = i0 + 8 + eg;
        bool vA = idxA < end, vB = idxB < end;
        int sA = csr_src[vA ? idxA : beg];
        int sB = csr_src[vB ? idxB : beg];
        float eA = el[(size_t)sA * NH + fg] + er_mine;
        float eB = el[(size_t)sB * NH + fg] + er_mine;
        eA = eA > 0.f ? eA : NEG_SLOPE * eA;
        eB = eB > 0.f ? eB : NEG_SLOPE * eB;
        float pA = vA ? __expf(eA) : 0.f;
        float pB = vB ? __expf(eB) : 0.f;
        ssum += pA + pB;
        const unsigned short* hpA = h + (size_t)sA * HF + fg * 32;
        const unsigned short* hpB = h + (size_t)sB * HF + fg * 32;
        bf16x8 va[4], vb[4];
        #pragma unroll
        for (int c = 0; c < 4; ++c) { va[c] = *(const bf16x8*)(hpA + c * 8); }
        #pragma unroll
        for (int c = 0; c < 4; ++c) { vb[c] = *(const bf16x8*)(hpB + c * 8); }
        #pragma unroll
        for (int c = 0; c < 4; ++c)
            #pragma unroll
            for (int k = 0; k < 8; ++k) {
                acc[c * 8 + k] = fmaf(bf2f((unsigned short)va[c][k]), pA, acc[c * 8 + k]);
                acc[c * 8 + k] = fmaf(bf2f((unsigned short)vb[c][k]), pB, acc[c * 8 + k]);
            }
    }

    // reduce ssum over edge slots (keep head bits)
    ssum += __shfl_xor(ssum, 8);
    ssum += __shfl_xor(ssum, 16);
    ssum += __shfl_xor(ssum, 32);
    float inv_s = (ssum > 0.f) ? 1.f / ssum : 0.f;

    // recursive-halving reduce-scatter over eg (static reg indices only)
    int e2 = (lane >> 5) & 1, e1 = (lane >> 4) & 1, e0 = (lane >> 3) & 1;
    float t16[16];
    #pragma unroll
    for (int j = 0; j < 16; ++j) {
        float keep = e2 ? acc[16 + j] : acc[j];
        float send = e2 ? acc[j] : acc[16 + j];
        t16[j] = keep + __shfl_xor(send, 32);
    }
    float t8[8];
    #pragma unroll
    for (int j = 0; j < 8; ++j) {
        float keep = e1 ? t16[8 + j] : t16[j];
        float send = e1 ? t16[j] : t16[8 + j];
        t8[j] = keep + __shfl_xor(send, 16);
    }
    float t4[4];
    #pragma unroll
    for (int j = 0; j < 4; ++j) {
        float keep = e0 ? t8[4 + j] : t8[j];
        float send = e0 ? t8[j] : t8[4 + j];
        t4[j] = keep + __shfl_xor(send, 8);
    }

    int col = fg * 32 + eg * 4;
    float4 bv = *(const float4*)&bias[col];
    float4 o = make_float4(fmaf(t4[0], inv_s, bv.x), fmaf(t4[1], inv_s, bv.y),
                           fmaf(t4[2], inv_s, bv.z), fmaf(t4[3], inv_s, bv.w));
    *(float4*)&out[(size_t)node * HF + col] = o;
}

extern "C" void kernel_launch(void* const* d_in, const int* in_sizes, int n_in,
                              void* d_out, int out_size, void* d_ws, size_t ws_size,
                              hipStream_t stream) {
    const float* feat = (const float*)d_in[0];
    const float* W    = (const float*)d_in[1];
    const float* al   = (const float*)d_in[2];
    const float* ar   = (const float*)d_in[3];
    const float* bias = (const float*)d_in[4];
    const int*   src  = (const int*)d_in[5];
    const int*   dst  = (const int*)d_in[6];
    float* out = (float*)d_out;

    char* ws = (char*)d_ws;
    size_t off = 0;
    unsigned short* h = (unsigned short*)(ws + off); off += (size_t)NN * HF * 2;     // 25.6 MB
    float* el = (float*)(ws + off);                  off += (size_t)NN * NH * 4;
    float* er = (float*)(ws + off);                  off += (size_t)NN * NH * 4;
    int* deg = (int*)(ws + off);                     off += (size_t)DEG_PAD * 4;
    int* row_ptr = (int*)(ws + off);                 off += (size_t)(NN + 1) * 4 + 60;
    off &= ~(size_t)63;
    int* cursor = (int*)(ws + off);                  off += (size_t)NN * 4;
    int* csr_src = (int*)(ws + off);                 off += (size_t)NE * 4;
    unsigned short* Wb = (unsigned short*)(ws + off); off += (size_t)IN_F * HF * 2;

    hipMemsetAsync(deg, 0, (size_t)DEG_PAD * 4, stream);

    wdeg_kernel<<<EDGE_BLOCKS, 256, 0, stream>>>(W, Wb, dst, deg);
    gemm_kernel<<<GEMM_BLOCKS, 256, 0, stream>>>(feat, Wb, h, NN);
    elr_kernel<<<ELR_BLOCKS, 256, 0, stream>>>(h, al, ar, el, er);
    scan_kernel<<<1, 1024, 0, stream>>>(deg, row_ptr, cursor);
    fill_kernel<<<EDGE_BLOCKS, 256, 0, stream>>>(src, dst, cursor, csr_src);
    agg_kernel<<<ELR_BLOCKS, 256, 0, stream>>>(h, el, er, row_ptr, csr_src, bias, out);
}